// Round 1
// baseline (68.841 us; speedup 1.0000x reference)
//
#include <hip/hip_runtime.h>
#include <hip/hip_bf16.h>
#include <math.h>

// Problem constants:
//   feature_map [B=2, H=38, W=38, C=512] float32 (NHWC, C contiguous)
//   rois        [B=2, N=64, 4] int32  (y, x, h, w), h,w >= P
//   out         [B, N, P, P, C] float32, P = 7
#define RB 2
#define RN 64
#define RH 38
#define RW 38
#define RC 512
#define RP 7
#define CELLS (RB * RN * RP * RP)  // 6272
#define CPI (RN * RP * RP)         // cells per image = 3136
#define PPI (CPI / 2)              // cell-pairs per image = 1568

__device__ __forceinline__ float4 max4(float4 a, float4 b) {
  return make_float4(fmaxf(a.x, b.x), fmaxf(a.y, b.y), fmaxf(a.z, b.z),
                     fmaxf(a.w, b.w));
}

// One WAVE per (cell, channel-half): 64 lanes x 1 float4 = 256 ch.
// 256-thread blocks -> 3136 blocks.
//
// Balance fix vs previous version: a block's two cells are q and q+1568 of
// the SAME image (different ROIs, decorrelated bin sizes) instead of two
// adjacent cells of the same ROI. Per-block work = mean of two independent
// draws -> no more 2x36-load monster blocks setting the CU long pole.
//
// Depth-8 software pipeline (8 loads in flight): covers the post-poison
// cold-L2 phase (~900 cy HBM latency) twice as deep as before; +16 VGPR,
// still far from any occupancy cliff.
//
// XCD swizzle (round-robin blockIdx%8 -> XCD assumed): image 0 -> XCDs 0-3,
// image 1 -> XCDs 4-7; each ~1.5 MB image fits the 4 MB per-XCD L2.
__global__ __launch_bounds__(256) void roi_pool_kernel(
    const float* __restrict__ fm, const int* __restrict__ rois,
    float* __restrict__ out) {
  int wv = threadIdx.x >> 6;     // 0..3
  int lane = threadIdx.x & 63;
  int half = wv & 1;             // channel half: 0 -> ch[0,256), 1 -> [256,512)

  int bx = blockIdx.x;           // [0, 3136)
  int x = bx & 7;                // presumed XCD
  int j = bx >> 3;               // [0, 392)
  int img = x >> 2;              // 0..1
  int q = (j << 2) | (x & 3);    // [0, 1568), bijective per image
  // waves 0,1 -> cell q of this image; waves 2,3 -> cell q+1568 (other ROI)
  int cell = img * CPI + q + (wv >> 1) * PPI;  // [0, 6272)

  int px = cell % RP;
  int t = cell / RP;
  int py = t % RP;
  t /= RP;                       // roi id = b*RN + n
  int b = t / RN;

  // Scalar-path roi fetch: uniform index -> SMEM load, scalar bin math.
  int rid = __builtin_amdgcn_readfirstlane(t);
  const int4 rv = *(const int4*)(rois + (rid << 2));
  int y0 = rv.x, x0 = rv.y, h = rv.z, w = rv.w;

  // Bin [ys,ye) x [xs,xe); bins partition the ROI exactly (h,w >= 7).
  int ys = (py * h) / RP, ye = ((py + 1) * h) / RP;
  int xs = (px * w) / RP, xe = ((px + 1) * w) / RP;
  int bw = xe - xs;
  int cnt = bw * (ye - ys);      // 1..36

  const float4* p =
      (const float4*)(fm +
                      (size_t)((b * RH + y0 + ys) * RW + x0 + xs) * RC) +
      (half << 6) + lane;
  const int pixstep = RC / 4;                  // 128 float4 per pixel
  const int wrapstep = (RW - bw) * (RC / 4);   // extra step at row wrap

#define STEP() \
  { p += pixstep; if (--xrem == 0) { xrem = bw; p += wrapstep; } }

  float4 m = make_float4(-INFINITY, -INFINITY, -INFINITY, -INFINITY);
  int xrem = bw;

  // Depth-8 pipeline. All branches wave-uniform (cnt/bw uniform per wave).
  float4 a0, a1, a2, a3, a4, a5, a6, a7;
  a0 = *p;
  if (cnt > 1) { STEP(); a1 = *p; }
  if (cnt > 2) { STEP(); a2 = *p; }
  if (cnt > 3) { STEP(); a3 = *p; }
  if (cnt > 4) { STEP(); a4 = *p; }
  if (cnt > 5) { STEP(); a5 = *p; }
  if (cnt > 6) { STEP(); a6 = *p; }
  if (cnt > 7) { STEP(); a7 = *p; }
  int rem = cnt - 8;
  while (rem > 0) {
    m = max4(m, a0);
    STEP(); a0 = *p; --rem;
    if (rem > 0) { m = max4(m, a1); STEP(); a1 = *p; --rem; }
    if (rem > 0) { m = max4(m, a2); STEP(); a2 = *p; --rem; }
    if (rem > 0) { m = max4(m, a3); STEP(); a3 = *p; --rem; }
    if (rem > 0) { m = max4(m, a4); STEP(); a4 = *p; --rem; }
    if (rem > 0) { m = max4(m, a5); STEP(); a5 = *p; --rem; }
    if (rem > 0) { m = max4(m, a6); STEP(); a6 = *p; --rem; }
    if (rem > 0) { m = max4(m, a7); STEP(); a7 = *p; --rem; }
  }
  m = max4(m, a0);
  if (cnt > 1) m = max4(m, a1);
  if (cnt > 2) m = max4(m, a2);
  if (cnt > 3) m = max4(m, a3);
  if (cnt > 4) m = max4(m, a4);
  if (cnt > 5) m = max4(m, a5);
  if (cnt > 6) m = max4(m, a6);
  if (cnt > 7) m = max4(m, a7);
#undef STEP

  // Normal (L2-cached) store: out is ~1.6 MB/XCD, L2 absorbs it faster than
  // NT writes pushed toward HBM.
  float4* o = (float4*)(out + (size_t)cell * RC) + (half << 6) + lane;
  *o = m;
}

extern "C" void kernel_launch(void* const* d_in, const int* in_sizes, int n_in,
                              void* d_out, int out_size, void* d_ws, size_t ws_size,
                              hipStream_t stream) {
  const float* fm = (const float*)d_in[0];
  const int* rois = (const int*)d_in[1];
  float* out = (float*)d_out;

  roi_pool_kernel<<<CELLS / 2, 256, 0, stream>>>(fm, rois, out);
}